// Round 8
// baseline (191.001 us; speedup 1.0000x reference)
//
#include <hip/hip_runtime.h>
#include <type_traits>

// Fused attention block for MI355X (gfx950).
// Pipeline: conv(x,W) + gates -> GEMM1(qkv, fused RMS/RoPE/shift/vgate epilogue) ->
//           windowed flash attention (S^T single-pass) -> GEMM2 -> d_out (f32)

#define TSEQ 8192
#define DIMM 1024
#define NHEAD 8
#define HD 128
#define ATTN_SCALE 0.1f
#define RMS_EPS 1.1920929e-07f

typedef __bf16 bfx2 __attribute__((ext_vector_type(2)));
typedef __bf16 bfx4 __attribute__((ext_vector_type(4)));
typedef __bf16 bfx8 __attribute__((ext_vector_type(8)));
typedef float f32x4 __attribute__((ext_vector_type(4)));
typedef short s16x4 __attribute__((ext_vector_type(4)));

#define GLDS16(g, l)                                                         \
  __builtin_amdgcn_global_load_lds(                                          \
      (const __attribute__((address_space(1))) void*)(g),                    \
      (__attribute__((address_space(3))) void*)(l), 16, 0, 0)

__device__ __forceinline__ float sig_(float z) { return 1.0f / (1.0f + __expf(-z)); }

// ---------------- f32 -> bf16 conversions ----------------
__global__ void k_conv_x(const float4* __restrict__ x, bfx4* __restrict__ xb, int n4) {
  int i = blockIdx.x * blockDim.x + threadIdx.x;
  int stride = gridDim.x * blockDim.x;
  for (; i < n4; i += stride) {
    float4 v = x[i];
    bfx4 o;
    o[0] = (__bf16)v.x; o[1] = (__bf16)v.y; o[2] = (__bf16)v.z; o[3] = (__bf16)v.w;
    xb[i] = o;
  }
}

__global__ void k_conv_w(const float4* __restrict__ w, const float* __restrict__ lam,
                         bfx4* __restrict__ w1b, bfx4* __restrict__ w2b) {
  const int n4 = 4096 * 1024 / 4;
  const float l0 = lam[0], l1 = lam[1];
  int i = blockIdx.x * blockDim.x + threadIdx.x;
  int stride = gridDim.x * blockDim.x;
  for (; i < n4; i += stride) {
    int row = (i * 4) >> 10;
    float s = (row < 3 * DIMM) ? l0 : l1;
    float4 v = w[i];
    bfx4 o;
    o[0] = (__bf16)(s * v.x); o[1] = (__bf16)(s * v.y);
    o[2] = (__bf16)(s * v.z); o[3] = (__bf16)(s * v.w);
    if (row < 3 * DIMM) w1b[i] = o;
    else                w2b[i - 3 * DIMM * DIMM / 4] = o;
  }
}

// ---------------- gate precompute: ag = sigmoid(x.agw), vg = 2*sigmoid(x.vgw) ----------------
__global__ void k_gates(const float* __restrict__ x, const float* __restrict__ agw,
                        const float* __restrict__ vgw, float* __restrict__ ag,
                        float* __restrict__ vg) {
  int idx = blockIdx.x * blockDim.x + threadIdx.x;  // t*8 + h
  if (idx >= TSEQ * NHEAD) return;
  int t = idx >> 3, h = idx & 7;
  float za = 0.0f, zg = 0.0f;
#pragma unroll
  for (int j = 0; j < 12; j++) {
    float xv = x[(size_t)t * DIMM + j];
    za += xv * agw[h * 12 + j];
    zg += xv * vgw[h * 12 + j];
  }
  ag[idx] = sig_(za);
  vg[idx] = 2.0f * sig_(zg);
}

// ---------------- interleaved 8-phase GEMM (+optional fused qkv epilogue) ----------------
// C[M,N] = A[M,K]*B[N,K]^T. BM x 256 tile, 8 waves (2x4), wave tile 64x64.
// EPI==0: plain C write. EPI==1: N=3072 qkv; bn<4 -> q (RMS+RoPE), bn<8 -> k
// (RMS+RoPE+key-shift), else v (ve-gate + LDS transpose -> vT).
template <int BM, typename CT, int EPI>
__global__ __launch_bounds__(512, 2) void k_gemm8i(
    const __bf16* __restrict__ A, const __bf16* __restrict__ B,
    CT* __restrict__ C, int M, int N, int K,
    __bf16* __restrict__ qb, __bf16* __restrict__ kb, __bf16* __restrict__ vT,
    const float* __restrict__ f1, const float* __restrict__ f2,
    const float* __restrict__ vg, const float* __restrict__ ve,
    const int* __restrict__ koff_p) {
  constexpr int BN = 256;
  constexpr int MF = BM / 32, NF = 4;
  constexpr int MH = MF / 2;
  constexpr int LA = BM / 128, LB = 2;
  __shared__ __align__(16) __bf16 lds0s[(BM + BN) * 64];
  __shared__ __align__(16) __bf16 lds1s[(BM + BN) * 64];
  char* lds0 = (char*)lds0s;
  char* lds1 = (char*)lds1s;

  const int tid = threadIdx.x;
  const int wave = tid >> 6, lane = tid & 63;
  const int wm = wave >> 2, wn = wave & 3;
  const int lr = lane & 15, lg = lane >> 4;
  const int bm = blockIdx.x, bn = blockIdx.y;

  const int srow = tid >> 3;
  const int scol = ((tid & 7) ^ (srow & 7)) * 8;  // pre-swizzled global col
  const __bf16* Ag = A + (size_t)(bm * BM + srow) * K + scol;
  const __bf16* Bg = B + (size_t)(bn * BN + srow) * K + scol;

  auto stageAu = [&](int kt, int u, char* buf) {
#pragma unroll
    for (int L = 0; L < LA; L++)
      GLDS16(Ag + (size_t)(u * (BM / 2) + L * 64) * K + kt * 64,
             buf + (u * (BM / 2) + L * 64) * 128 + wave * 1024);
  };
  auto stageBu = [&](int kt, int u, char* buf) {
#pragma unroll
    for (int L = 0; L < LB; L++)
      GLDS16(Bg + (size_t)(u * 128 + L * 64) * K + kt * 64,
             buf + BM * 128 + (u * 128 + L * 64) * 128 + wave * 1024);
  };

  const int aoffs = (wm * (BM / 2) + lr) * 128;
  const int boffs = BM * 128 + (wn * 64 + lr) * 128;
  const int s0 = (lg ^ (lr & 7)) * 16;
  const int s1 = ((4 + lg) ^ (lr & 7)) * 16;

  f32x4 acc[MF][NF] = {};
  bfx8 af[MH][2], bfr[NF][2];

  auto readAf = [&](int i, const char* rbuf, int hf) {
    const char* p = rbuf + aoffs + (hf * MH + i) * 2048;
    af[i][0] = *(const bfx8*)(p + s0);
    af[i][1] = *(const bfx8*)(p + s1);
  };
  auto readBf = [&](int f, const char* rbuf) {
    const char* p = rbuf + boffs + f * 2048;
    bfr[f][0] = *(const bfx8*)(p + s0);
    bfr[f][1] = *(const bfx8*)(p + s1);
  };
  auto mfma2 = [&](int ha, int hb, int i, int j) {
    acc[ha * MH + i][hb * 2 + j] = __builtin_amdgcn_mfma_f32_16x16x32_bf16(
        af[i][0], bfr[hb * 2 + j][0], acc[ha * MH + i][hb * 2 + j], 0, 0, 0);
    acc[ha * MH + i][hb * 2 + j] = __builtin_amdgcn_mfma_f32_16x16x32_bf16(
        af[i][1], bfr[hb * 2 + j][1], acc[ha * MH + i][hb * 2 + j], 0, 0, 0);
  };
  auto clusterPlain = [&](int ha, int hb) {
    __builtin_amdgcn_s_setprio(1);
#pragma unroll
    for (int i = 0; i < MH; i++) { mfma2(ha, hb, i, 0); mfma2(ha, hb, i, 1); }
    __builtin_amdgcn_s_setprio(0);
  };
  auto clusterA_r = [&](int ha, int hb, const char* rbuf, int hf) {
    __builtin_amdgcn_s_setprio(1);
#pragma unroll
    for (int i = 0; i < MH; i++) {
      mfma2(ha, hb, i, 0); mfma2(ha, hb, i, 1);
      readAf(i, rbuf, hf);
      __builtin_amdgcn_sched_group_barrier(0x8, 4, 0);
      __builtin_amdgcn_sched_group_barrier(0x100, 2, 0);
    }
    __builtin_amdgcn_s_setprio(0);
  };
  auto clusterB_r = [&](int ha, int hb, const char* rbuf) {
    __builtin_amdgcn_s_setprio(1);
#pragma unroll
    for (int j = 0; j < 2; j++) {
#pragma unroll
      for (int i = 0; i < MH; i++) mfma2(ha, hb, i, j);
      readBf(hb * 2 + j, rbuf);
      __builtin_amdgcn_sched_group_barrier(0x8, MH * 2, 0);
      __builtin_amdgcn_sched_group_barrier(0x100, 2, 0);
    }
    __builtin_amdgcn_s_setprio(0);
  };

#define BAR() __builtin_amdgcn_s_barrier()
#define VMC(n) asm volatile("s_waitcnt vmcnt(%0)" ::"i"(n) : "memory")

  stageAu(0, 0, lds0); stageAu(0, 1, lds0);
  stageBu(0, 0, lds0); stageBu(0, 1, lds0);
  stageBu(1, 0, lds1); stageBu(1, 1, lds1);
  VMC(2 * LB); BAR();
#pragma unroll
  for (int i = 0; i < MH; i++) readAf(i, lds0, 0);
#pragma unroll
  for (int f = 0; f < 4; f++) readBf(f, lds0);

  int jj = 0;
  auto run_iter = [&](auto more_c) {
    constexpr bool more = decltype(more_c)::value;
    const int t1 = 2 * jj + 1, t2 = t1 + 1, t3 = t1 + 2;
    stageAu(t1, 0, lds1);
    clusterPlain(0, 0);
    BAR();
    stageAu(t1, 1, lds1);
    clusterA_r(0, 1, lds0, 1);
    VMC(2 * LA); BAR();
    if constexpr (more) stageBu(t2, 0, lds0);
    clusterB_r(1, 0, lds1);
    VMC(more ? LB : 0); BAR();
    if constexpr (more) stageBu(t2, 1, lds0);
    clusterA_r(1, 1, lds1, 0);
    readBf(2, lds1); readBf(3, lds1);
    BAR();
    if constexpr (more) stageAu(t2, 0, lds0);
    clusterPlain(0, 0);
    BAR();
    if constexpr (more) stageAu(t2, 1, lds0);
    clusterA_r(0, 1, lds1, 1);
    if constexpr (more) { VMC(2 * LA); }
    BAR();
    if constexpr (more) {
      stageBu(t3, 0, lds1);
      clusterB_r(1, 0, lds0);
      VMC(LB);
    } else {
      clusterPlain(1, 0);
    }
    BAR();
    if constexpr (more) {
      stageBu(t3, 1, lds1);
      clusterA_r(1, 1, lds0, 0);
      readBf(2, lds0); readBf(3, lds0);
    } else {
      clusterPlain(1, 1);
    }
    BAR();
    jj++;
  };

  const int NT2 = K / 128;
  for (int j = 0; j < NT2 - 1; j++) run_iter(std::integral_constant<bool, true>{});
  run_iter(std::integral_constant<bool, false>{});

  if constexpr (EPI == 0) {
    // plain C write: C/D layout col = lane&15, row = (lane>>4)*4 + reg
    const int rbase = bm * BM + wm * (BM / 2) + lg * 4;
    const int cbase = bn * BN + wn * 64 + lr;
#pragma unroll
    for (int f = 0; f < MF; f++)
#pragma unroll
      for (int rr = 0; rr < 4; rr++) {
        size_t rowoff = (size_t)(rbase + f * 16 + rr) * N + cbase;
#pragma unroll
        for (int nf = 0; nf < NF; nf++) C[rowoff + nf * 16] = (CT)acc[f][nf][rr];
      }
  } else {
    const int third = bn >> 2;  // 0=q 1=k 2=v
    const int t0 = bm * BM;
    __syncthreads();  // GEMM LDS dead; reuse below
    if (third < 2) {
      // ---- RMS over d=128 (this wave's 64 cols + partner wave wn^1) ----
      float sums[MF][4];
#pragma unroll
      for (int f = 0; f < MF; f++)
#pragma unroll
        for (int rr = 0; rr < 4; rr++) {
          float s = 0.0f;
#pragma unroll
          for (int nf = 0; nf < NF; nf++) { float a = acc[f][nf][rr]; s += a * a; }
          s += __shfl_xor(s, 1); s += __shfl_xor(s, 2);
          s += __shfl_xor(s, 4); s += __shfl_xor(s, 8);
          sums[f][rr] = s;
        }
      float* rmsb = (float*)lds0;  // [8 waves][64 rows]
      if (lr == 0) {
#pragma unroll
        for (int f = 0; f < MF; f++)
#pragma unroll
          for (int rr = 0; rr < 4; rr++)
            rmsb[wave * 64 + f * 16 + lg * 4 + rr] = sums[f][rr];
      }
      __syncthreads();
      const int koff = *koff_p;
#pragma unroll
      for (int f = 0; f < MF; f++) {
#pragma unroll
        for (int rr = 0; rr < 4; rr++) {
          const int t = t0 + wm * 64 + f * 16 + lg * 4 + rr;
          float tot = sums[f][rr] + rmsb[(wave ^ 1) * 64 + f * 16 + lg * 4 + rr];
          float rn = rsqrtf(tot * (1.0f / 128.0f) + RMS_EPS);
#pragma unroll
          for (int nf = 0; nf < NF; nf++) {
            float v = acc[f][nf][rr] * rn;
            float vp = __shfl_xor(v, 1);  // RoPE pair: d parity == lr parity
            const int dcol = (bn & 3) * 256 + wn * 64 + nf * 16 + lr;  // 0..1023
            const int dh = dcol & 127;
            float o = f1[(size_t)t * HD + dh] * v + f2[(size_t)t * HD + dh] * vp;
            if (third == 0) {
              qb[(size_t)t * DIMM + dcol] = (__bf16)o;
            } else if (!koff || dh < 64) {
              kb[(size_t)t * DIMM + dcol] = (__bf16)o;
            } else {
              if (t + 1 < TSEQ) kb[(size_t)(t + 1) * DIMM + dcol] = (__bf16)o;
              if (t == 0)       kb[dcol] = (__bf16)o;
            }
          }
        }
      }
    } else {
      // ---- v: ve-gate then LDS transpose -> coalesced vT writes ----
      __bf16* trans = (__bf16*)lds0;  // [128 d][136 t-stride]
      const int h0 = (bn - 8) * 2;
#pragma unroll
      for (int pass = 0; pass < 2; pass++) {
        const int hg = h0 + pass;
        if ((wn >> 1) == pass) {
#pragma unroll
          for (int f = 0; f < MF; f++)
#pragma unroll
            for (int rr = 0; rr < 4; rr++) {
              const int tl = wm * 64 + f * 16 + lg * 4 + rr;
              const int t = t0 + tl;
              float gv = vg[(size_t)t * NHEAD + hg];
#pragma unroll
              for (int nf = 0; nf < NF; nf++) {
                const int cl = (wn & 1) * 64 + nf * 16 + lr;  // d within head
                float vev = ve[(size_t)t * DIMM + hg * HD + cl];
                trans[cl * 136 + tl] = (__bf16)(acc[f][nf][rr] + gv * vev);
              }
            }
        }
        __syncthreads();
#pragma unroll
        for (int rnd = 0; rnd < 4; rnd++) {
          const int row = rnd * 32 + (tid >> 4);
          const int tc = (tid & 15) * 8;
          bfx8 vv = *(const bfx8*)&trans[row * 136 + tc];
          *(bfx8*)&vT[(size_t)(hg * HD + row) * TSEQ + t0 + tc] = vv;
        }
        __syncthreads();
      }
    }
  }
#undef BAR
#undef VMC
}

// ---------------- windowed varlen flash attention, S^T single-pass ----------------
__global__ __launch_bounds__(256, 4) void k_attn2(
    const __bf16* __restrict__ qb, const __bf16* __restrict__ kb,
    const __bf16* __restrict__ vT, const float* __restrict__ ag,
    const int* __restrict__ sl, int ns, __bf16* __restrict__ yb) {
  const int h = blockIdx.y;
  const int w = threadIdx.x >> 6, l = threadIdx.x & 63;
  const int lr = l & 15, lg = l >> 4;
  const int q0r = (blockIdx.x * 4 + w) * 16;
  const int kbase = q0r - 128;
  const int q = q0r + lr;
  const int kfs = (q0r < 128) ? ((128 - q0r) >> 4) : 0;

  bfx8 qf[4];
#pragma unroll
  for (int ds = 0; ds < 4; ds++)
    qf[ds] = *(const bfx8*)&qb[(size_t)q * DIMM + h * HD + ds * 32 + lg * 8];

  int segs = 0;
  for (int i = 0; i < ns; i++) {
    int v = sl[i];
    segs = (v <= q) ? ((v > segs) ? v : segs) : segs;
  }
  int klo = q - 128;
  if (segs > klo) klo = segs;
  if (klo < 0) klo = 0;

  f32x4 sf[9] = {};
#pragma unroll
  for (int kf = 0; kf < 9; kf++) {
    if (kf >= kfs) {
      const int krow = kbase + kf * 16 + lr;
      const __bf16* kp = &kb[(size_t)krow * DIMM + h * HD + lg * 8];
      bfx8 k0 = *(const bfx8*)(kp);
      bfx8 k1 = *(const bfx8*)(kp + 32);
      bfx8 k2 = *(const bfx8*)(kp + 64);
      bfx8 k3 = *(const bfx8*)(kp + 96);
      sf[kf] = __builtin_amdgcn_mfma_f32_16x16x32_bf16(k0, qf[0], sf[kf], 0, 0, 0);
      sf[kf] = __builtin_amdgcn_mfma_f32_16x16x32_bf16(k1, qf[1], sf[kf], 0, 0, 0);
      sf[kf] = __builtin_amdgcn_mfma_f32_16x16x32_bf16(k2, qf[2], sf[kf], 0, 0, 0);
      sf[kf] = __builtin_amdgcn_mfma_f32_16x16x32_bf16(k3, qf[3], sf[kf], 0, 0, 0);
    }
  }

#pragma unroll
  for (int kf = 0; kf < 9; kf++)
#pragma unroll
    for (int rr = 0; rr < 4; rr++) {
      int k = kbase + kf * 16 + lg * 4 + rr;
      bool valid = (k >= klo) && (k <= q);
      sf[kf][rr] = valid ? sf[kf][rr] * ATTN_SCALE : -1e30f;
    }

  float mx = -1e30f;
#pragma unroll
  for (int kf = 0; kf < 9; kf++)
#pragma unroll
    for (int rr = 0; rr < 4; rr++) mx = fmaxf(mx, sf[kf][rr]);
  mx = fmaxf(mx, __shfl_xor(mx, 16));
  mx = fmaxf(mx, __shfl_xor(mx, 32));

  float lsum = 0.0f;
#pragma unroll
  for (int kf = 0; kf < 9; kf++)
#pragma unroll
    for (int rr = 0; rr < 4; rr++) {
      float p = __expf(sf[kf][rr] - mx);
      sf[kf][rr] = p;
      lsum += p;
    }
  lsum += __shfl_xor(lsum, 16);
  lsum += __shfl_xor(lsum, 32);

  f32x4 o[8] = {};
#pragma unroll
  for (int kf = 0; kf < 9; kf++) {
    if (kf >= kfs) {
      bfx4 pc;
      pc[0] = (__bf16)sf[kf][0]; pc[1] = (__bf16)sf[kf][1];
      pc[2] = (__bf16)sf[kf][2]; pc[3] = (__bf16)sf[kf][3];
      s16x4 pb = *(s16x4*)&pc;
      const int kk = kbase + kf * 16 + 4 * lg;
#pragma unroll
      for (int nf = 0; nf < 8; nf++) {
        s16x4 vf = *(const s16x4*)&vT[(size_t)(h * HD + nf * 16 + lr) * TSEQ + kk];
        o[nf] = __builtin_amdgcn_mfma_f32_16x16x16bf16_1k(vf, pb, o[nf], 0, 0, 0);
      }
    }
  }

  const float sc = ag[(size_t)q * NHEAD + h] / lsum;
#pragma unroll
  for (int nf = 0; nf < 8; nf++) {
    bfx4 st;
#pragma unroll
    for (int rr = 0; rr < 4; rr++) st[rr] = (__bf16)(o[nf][rr] * sc);
    *(bfx4*)&yb[(size_t)q * DIMM + h * HD + nf * 16 + lg * 4] = st;
  }
}

// ---------------- launch ----------------
extern "C" void kernel_launch(void* const* d_in, const int* in_sizes, int n_in,
                              void* d_out, int out_size, void* d_ws, size_t ws_size,
                              hipStream_t stream) {
  const float* x   = (const float*)d_in[0];
  const float* qw  = (const float*)d_in[1];
  const float* ve  = (const float*)d_in[2];
  const float* lam = (const float*)d_in[3];
  const float* f1  = (const float*)d_in[4];
  const float* f2  = (const float*)d_in[5];
  const float* agw = (const float*)d_in[6];
  const float* vgw = (const float*)d_in[7];
  const int*   sl  = (const int*)d_in[8];
  const int    ns  = in_sizes[8];
  const int*   koff = (const int*)d_in[10];
  float* out = (float*)d_out;
  char* ws = (char*)d_ws;

  // workspace: xb 16M | w1b 6M | w2b 2M | qbuf 16M | kbuf 16M | vT 16M | ybuf 16M | ag/vg
  const size_t MB = 1024 * 1024;
  if (ws_size < 90 * MB) return;
  __bf16* xb   = (__bf16*)(ws);
  __bf16* w1b  = (__bf16*)(ws + 16 * MB);
  __bf16* w2b  = (__bf16*)(ws + 22 * MB);
  __bf16* qbuf = (__bf16*)(ws + 24 * MB);
  __bf16* kbuf = (__bf16*)(ws + 40 * MB);
  __bf16* vT   = (__bf16*)(ws + 56 * MB);
  __bf16* ybuf = (__bf16*)(ws + 72 * MB);
  float*  ag   = (float*)(ws + 88 * MB);
  float*  vg   = (float*)(ws + 88 * MB + 256 * 1024);

  k_conv_x<<<2048, 256, 0, stream>>>((const float4*)x, (bfx4*)xb, TSEQ * DIMM / 4);
  k_conv_w<<<1024, 256, 0, stream>>>((const float4*)qw, lam, (bfx4*)w1b, (bfx4*)w2b);
  k_gates<<<TSEQ * NHEAD / 256, 256, 0, stream>>>(x, agw, vgw, ag, vg);
  k_gemm8i<128, __bf16, 1><<<dim3(TSEQ / 128, 3 * DIMM / 256), 512, 0, stream>>>(
      xb, w1b, ((__bf16*)nullptr), TSEQ, 3 * DIMM, DIMM,
      qbuf, kbuf, vT, f1, f2, vg, ve, koff);
  k_attn2<<<dim3(TSEQ / 64, NHEAD), 256, 0, stream>>>(qbuf, kbuf, vT, ag, sl, ns, ybuf);
  k_gemm8i<128, float, 0><<<dim3(TSEQ / 128, DIMM / 256), 512, 0, stream>>>(
      ybuf, w2b, out, TSEQ, DIMM, DIMM,
      nullptr, nullptr, nullptr, nullptr, nullptr, nullptr, nullptr, nullptr);
}